// Round 5
// baseline (400.879 us; speedup 1.0000x reference)
//
#include <hip/hip_runtime.h>
#include <cstdint>

#define BB 8
#define LL 4096
#define DD 1024
#define HH 16
#define KSEL 409
#define NT3 3072
#define MTOT (BB * KSEL)   // 3272 flat selected rows
#define PA 36              // padded A pitch (u16) for k_score reg-staged A
#define VP 448             // vT key-pitch

typedef unsigned short u16;
typedef unsigned int u32;
typedef __attribute__((ext_vector_type(4))) unsigned int ux4;
typedef __attribute__((ext_vector_type(4))) unsigned short us4;
typedef __attribute__((ext_vector_type(8))) short short8;
typedef __attribute__((ext_vector_type(4))) float f32x4;

typedef const u32 __attribute__((address_space(1)))* gas_p;
typedef u32 __attribute__((address_space(3)))* las_p;

__device__ __forceinline__ void dma16(const void* g, void* l) {
  __builtin_amdgcn_global_load_lds((gas_p)g, (las_p)l, 16, 0, 0);
}

__device__ __forceinline__ u16 bfh(float f) {
  unsigned u = __float_as_uint(f);
  return (u16)((u + 0x7fffu + ((u >> 16) & 1u)) >> 16);
}
__device__ __forceinline__ float bff(u16 h) { return __uint_as_float(((unsigned)h) << 16); }

__device__ __forceinline__ void cvt8(const float* v, ux4& H, ux4& L) {
#pragma unroll
  for (int i = 0; i < 4; i++) {
    u16 h0 = bfh(v[2 * i]), h1 = bfh(v[2 * i + 1]);
    u16 l0 = bfh(v[2 * i] - bff(h0));
    u16 l1 = bfh(v[2 * i + 1] - bff(h1));
    H[i] = (unsigned)h0 | ((unsigned)h1 << 16);
    L[i] = (unsigned)l0 | ((unsigned)l1 << 16);
  }
}

// ---------- prep: fp32 weight [K][N] -> split-bf16 K-packed, chunk-swizzled ----
// layout: [s][n][32] u16, 16B chunk q stored at q ^ ((n>>1)&3)
__global__ __launch_bounds__(256) void k_prep(const float* __restrict__ w, int N,
                                              u16* __restrict__ h, u16* __restrict__ l) {
  __shared__ float T[32][257];
  const int t = threadIdx.x;
  const int n0 = blockIdx.x * 256, s = blockIdx.y;
#pragma unroll 4
  for (int r = 0; r < 32; r++) T[r][t] = w[((long)(s * 32 + r)) * N + n0 + t];
  __syncthreads();
  const int n = n0 + t;
  const int swz = (n >> 1) & 3;
  const long base = ((long)s * N + n) * 32;
#pragma unroll
  for (int q = 0; q < 4; q++) {
    float v[8];
#pragma unroll
    for (int i = 0; i < 8; i++) v[i] = T[q * 8 + i][t];
    ux4 H, L;
    cvt8(v, H, L);
    *(ux4*)(h + base + (q ^ swz) * 8) = H;
    *(ux4*)(l + base + (q ^ swz) * 8) = L;
  }
}

// ---------- scorer: BM=128, BN=256, 512 thr; B via DMA dbuf, A reg-staged -----
// dyn LDS (u16): AH[2][128*36] @0, AL @9216, BH[2][256*32] @18432, BL @34816,
// zp(float[128][4]) @51200 -> 104448 bytes
__global__ __launch_bounds__(512) void k_score(
    const float* __restrict__ x, const u16* __restrict__ w1h, const u16* __restrict__ w1l,
    const float* __restrict__ b1, const float* __restrict__ w2,
    float* __restrict__ z, float* __restrict__ y) {
  extern __shared__ u16 sm[];
  u16* AH = sm;
  u16* AL = sm + 9216;
  u16* BH = sm + 18432;
  u16* BL = sm + 34816;
  float* zp = (float*)(sm + 51200);
  const int t = threadIdx.x;
  const long t0 = (long)blockIdx.x * 128;
  const int w = t >> 6, lane = t & 63;
  const int wy = w >> 2, wx = w & 3;
  const int g = lane >> 4, qi = lane & 15;
  const int swz = (qi >> 1) & 3;
  f32x4 acc[4][4];
#pragma unroll
  for (int i = 0; i < 4; i++)
#pragma unroll
    for (int j = 0; j < 4; j++) acc[i][j] = (f32x4){0.f, 0.f, 0.f, 0.f};

  const int ar = t >> 2, ac = t & 3;           // A: row, chunk
  const float* xrow = x + (t0 + ar) * DD + ac * 8;
  float* yrow = y + (t0 + ar) * DD + ac * 8;

  // helpers -------------------------------------------------------------
  auto BDMA = [&](int buf, int s) {
    // rows w*32 + i*16 + (l>>2), chunk l&3 ; lds base: w*1024 + i*512 (u16)
#pragma unroll
    for (int i = 0; i < 2; i++) {
      const int row = w * 32 + i * 16 + (lane >> 2);
      const u16* gh = w1h + ((long)s * 256 + row) * 32 + (lane & 3) * 8;
      const u16* gl = w1l + ((long)s * 256 + row) * 32 + (lane & 3) * 8;
      u16* lh = BH + buf * 8192 + w * 1024 + i * 512;
      u16* ll = BL + buf * 8192 + w * 1024 + i * 512;
      dma16(gh, lh);
      dma16(gl, ll);
    }
  };
  auto AWRITE = [&](int buf, const float4& va, const float4& vb) {
    float v[8] = {va.x, va.y, va.z, va.w, vb.x, vb.y, vb.z, vb.w};
    ux4 H, L;
    cvt8(v, H, L);
    *(ux4*)(AH + buf * 4608 + ar * PA + ac * 8) = H;
    *(ux4*)(AL + buf * 4608 + ar * PA + ac * 8) = L;
  };

  // prologue: stage s=0 into buf0
  {
    float4 va = *(const float4*)(xrow);
    float4 vb = *(const float4*)(xrow + 4);
    *(float4*)(yrow) = va;
    *(float4*)(yrow + 4) = vb;
    AWRITE(0, va, vb);
    BDMA(0, 0);
  }
  __syncthreads();
  int cur = 0;
  for (int s = 0; s < 32; s++) {
    float4 va, vb;
    if (s < 31) {
      BDMA(cur ^ 1, s + 1);
      va = *(const float4*)(xrow + (s + 1) * 32);
      vb = *(const float4*)(xrow + (s + 1) * 32 + 4);
    }
    // compute on buf cur
    short8 a_h[4], a_l[4];
#pragma unroll
    for (int mi = 0; mi < 4; mi++) {
      const int idx = cur * 4608 + (wy * 64 + mi * 16 + qi) * PA + g * 8;
      a_h[mi] = *(const short8*)(AH + idx);
      a_l[mi] = *(const short8*)(AL + idx);
    }
#pragma unroll
    for (int ni = 0; ni < 4; ni++) {
      const int idx = cur * 8192 + (wx * 64 + ni * 16 + qi) * 32 + (g ^ swz) * 8;
      short8 b_h = *(const short8*)(BH + idx);
      short8 b_l = *(const short8*)(BL + idx);
#pragma unroll
      for (int mi = 0; mi < 4; mi++) {
        acc[mi][ni] = __builtin_amdgcn_mfma_f32_16x16x32_bf16(a_h[mi], b_h, acc[mi][ni], 0, 0, 0);
        acc[mi][ni] = __builtin_amdgcn_mfma_f32_16x16x32_bf16(a_h[mi], b_l, acc[mi][ni], 0, 0, 0);
        acc[mi][ni] = __builtin_amdgcn_mfma_f32_16x16x32_bf16(a_l[mi], b_h, acc[mi][ni], 0, 0, 0);
        acc[mi][ni] = __builtin_amdgcn_mfma_f32_16x16x32_bf16(a_l[mi], b_l, acc[mi][ni], 0, 0, 0);
      }
    }
    if (s < 31) {
      *(float4*)(yrow + (s + 1) * 32) = va;
      *(float4*)(yrow + (s + 1) * 32 + 4) = vb;
      AWRITE(cur ^ 1, va, vb);
    }
    __syncthreads();
    cur ^= 1;
  }
  // epilogue: relu + layer-2 (fp32), reduce over qi then across col-waves
  float part[4][4];
#pragma unroll
  for (int mi = 0; mi < 4; mi++)
#pragma unroll
    for (int r = 0; r < 4; r++) part[mi][r] = 0.f;
#pragma unroll
  for (int ni = 0; ni < 4; ni++) {
    const int col = wx * 64 + ni * 16 + qi;
    const float b1v = b1[col], w2v = w2[col];
#pragma unroll
    for (int mi = 0; mi < 4; mi++)
#pragma unroll
      for (int r = 0; r < 4; r++) {
        float hv = acc[mi][ni][r] + b1v;
        hv = hv > 0.f ? hv : 0.f;
        part[mi][r] = fmaf(hv, w2v, part[mi][r]);
      }
  }
#pragma unroll
  for (int mi = 0; mi < 4; mi++)
#pragma unroll
    for (int r = 0; r < 4; r++) {
      float p = part[mi][r];
      p += __shfl_xor(p, 1, 16);
      p += __shfl_xor(p, 2, 16);
      p += __shfl_xor(p, 4, 16);
      p += __shfl_xor(p, 8, 16);
      part[mi][r] = p;
    }
  if (qi == 0) {
#pragma unroll
    for (int mi = 0; mi < 4; mi++)
#pragma unroll
      for (int r = 0; r < 4; r++)
        zp[(wy * 64 + mi * 16 + g * 4 + r) * 4 + wx] = part[mi][r];
  }
  __syncthreads();
  if (t < 128) z[t0 + t] = (zp[t * 4] + zp[t * 4 + 1]) + (zp[t * 4 + 2] + zp[t * 4 + 3]);
}

// ---------- per-batch top-k via bitonic sort ----------
__global__ __launch_bounds__(1024) void k_topk(const float* __restrict__ z,
                                               int* __restrict__ sel) {
  __shared__ unsigned long long keys[LL];
  __shared__ unsigned int si[512];
  const int b = blockIdx.x;
  const int tid = threadIdx.x;
#pragma unroll
  for (int s = 0; s < 4; s++) {
    const int i = tid + s * 1024;
    unsigned int u = __float_as_uint(z[b * LL + i]);
    u = (u & 0x80000000u) ? ~u : (u | 0x80000000u);
    keys[i] = ((unsigned long long)u << 32) | (unsigned int)(LL - 1 - i);
  }
  __syncthreads();
  for (unsigned int k = 2; k <= LL; k <<= 1) {
    for (unsigned int j = k >> 1; j > 0; j >>= 1) {
#pragma unroll
      for (int s = 0; s < 4; s++) {
        const unsigned int i = tid + s * 1024;
        const unsigned int ixj = i ^ j;
        if (ixj > i) {
          const bool up = ((i & k) == 0);
          const unsigned long long a = keys[i], c = keys[ixj];
          if ((a > c) == up) { keys[i] = c; keys[ixj] = a; }
        }
      }
      __syncthreads();
    }
  }
  if (tid < 512)
    si[tid] = (tid < KSEL) ? (unsigned int)(LL - 1) -
                                 (unsigned int)(keys[LL - KSEL + tid] & 0xFFFFFFFFu)
                           : 0xFFFFFFFFu;
  __syncthreads();
  for (unsigned int k = 2; k <= 512; k <<= 1) {
    for (unsigned int j = k >> 1; j > 0; j >>= 1) {
      if (tid < 512) {
        const unsigned int i = tid;
        const unsigned int ixj = i ^ j;
        if (ixj > i) {
          const bool up = ((i & k) == 0);
          const unsigned int a = si[i], c = si[ixj];
          if ((a > c) == up) { si[i] = c; si[ixj] = a; }
        }
      }
      __syncthreads();
    }
  }
  if (tid < KSEL) sel[b * KSEL + tid] = (int)si[tid];
}

// ---------- gather + split-convert selected rows, chunk-swizzled ----------
__global__ __launch_bounds__(256) void k_xsel(const float* __restrict__ x,
                                              const int* __restrict__ sel,
                                              u16* __restrict__ xsh, u16* __restrict__ xsl) {
  const int t = threadIdx.x;
  const int r = blockIdx.x * 8 + (t >> 5);   // 409 blocks * 8 = 3272 exactly
  const int sgrp = (t & 31);                 // k-step group (32 u16)
  const int b = r / KSEL;
  const int tok = sel[r];
  const int swz = (r >> 1) & 3;
  const float* src = x + ((long)b * LL + tok) * DD + sgrp * 32;
  u16* dh = xsh + (long)r * DD + sgrp * 32;
  u16* dl = xsl + (long)r * DD + sgrp * 32;
#pragma unroll
  for (int q = 0; q < 4; q++) {
    float4 f0 = *(const float4*)(src + q * 8);
    float4 f1 = *(const float4*)(src + q * 8 + 4);
    float v[8] = {f0.x, f0.y, f0.z, f0.w, f1.x, f1.y, f1.z, f1.w};
    ux4 H, L;
    cvt8(v, H, L);
    *(ux4*)(dh + (q ^ swz) * 8) = H;
    *(ux4*)(dl + (q ^ swz) * 8) = L;
  }
}

// ---------- qkv: full-DMA dbuf 128x128; writes split-bf16 Q,K + V^T ----------
// dyn LDS (u16): AH[2][4096]@0, AL@8192, BH@16384, BL@24576 -> 65536 bytes
__global__ __launch_bounds__(256) void k_qkv(
    const u16* __restrict__ xsh, const u16* __restrict__ xsl,
    const u16* __restrict__ wh, const u16* __restrict__ wl,
    u16* __restrict__ qh, u16* __restrict__ ql,
    u16* __restrict__ kh, u16* __restrict__ kl,
    u16* __restrict__ vTh, u16* __restrict__ vTl) {
  extern __shared__ u16 sm[];
  u16* AH = sm;
  u16* AL = sm + 8192;
  u16* BH = sm + 16384;
  u16* BL = sm + 24576;
  const int t = threadIdx.x;
  const int nt = blockIdx.x, r0 = blockIdx.y * 128;
  const int w = t >> 6, lane = t & 63;
  const int wy = w >> 1, wx = w & 1;
  const int qi = lane & 15, g = lane >> 4;
  const int swz = (qi >> 1) & 3;
  f32x4 acc[4][4];
#pragma unroll
  for (int i = 0; i < 4; i++)
#pragma unroll
    for (int j = 0; j < 4; j++) acc[i][j] = (f32x4){0.f, 0.f, 0.f, 0.f};

  auto STAGE = [&](int buf, int s) {
#pragma unroll
    for (int i = 0; i < 2; i++) {
      const int row = w * 32 + i * 16 + (lane >> 2);
      int rg = r0 + row;
      rg = rg < MTOT ? rg : MTOT - 1;
      const int ch = (lane & 3) * 8;
      const int lo = w * 1024 + i * 512;
      dma16(xsh + (long)rg * DD + s * 32 + ch, AH + buf * 4096 + lo);
      dma16(xsl + (long)rg * DD + s * 32 + ch, AL + buf * 4096 + lo);
      const long wb = ((long)s * NT3 + nt * 128 + row) * 32 + ch;
      dma16(wh + wb, BH + buf * 4096 + lo);
      dma16(wl + wb, BL + buf * 4096 + lo);
    }
  };

  STAGE(0, 0);
  __syncthreads();
  int cur = 0;
  for (int s = 0; s < 32; s++) {
    if (s < 31) STAGE(cur ^ 1, s + 1);
    short8 a_h[4], a_l[4];
#pragma unroll
    for (int mi = 0; mi < 4; mi++) {
      const int idx = cur * 4096 + (wy * 64 + mi * 16 + qi) * 32 + (g ^ swz) * 8;
      a_h[mi] = *(const short8*)(AH + idx);
      a_l[mi] = *(const short8*)(AL + idx);
    }
#pragma unroll
    for (int ni = 0; ni < 4; ni++) {
      const int idx = cur * 4096 + (wx * 64 + ni * 16 + qi) * 32 + (g ^ swz) * 8;
      short8 b_h = *(const short8*)(BH + idx);
      short8 b_l = *(const short8*)(BL + idx);
#pragma unroll
      for (int mi = 0; mi < 4; mi++) {
        acc[mi][ni] = __builtin_amdgcn_mfma_f32_16x16x32_bf16(a_h[mi], b_h, acc[mi][ni], 0, 0, 0);
        acc[mi][ni] = __builtin_amdgcn_mfma_f32_16x16x32_bf16(a_h[mi], b_l, acc[mi][ni], 0, 0, 0);
        acc[mi][ni] = __builtin_amdgcn_mfma_f32_16x16x32_bf16(a_l[mi], b_h, acc[mi][ni], 0, 0, 0);
      }
    }
    __syncthreads();
    cur ^= 1;
  }
  // epilogue: split-bf16 outputs; q/k row-major, v transposed [bh][d][key]
#pragma unroll
  for (int mi = 0; mi < 4; mi++) {
#pragma unroll
    for (int rr = 0; rr < 4; rr++) {
      const int r = r0 + wy * 64 + mi * 16 + g * 4 + rr;
      if (r < MTOT) {
        if (nt < 16) {
          u16* dh = (nt < 8) ? qh : kh;
          u16* dl = (nt < 8) ? ql : kl;
          const long base = (long)r * DD + (nt & 7) * 128 + wx * 64 + qi;
#pragma unroll
          for (int ni = 0; ni < 4; ni++) {
            const float f = acc[mi][ni][rr];
            const u16 hh_ = bfh(f);
            dh[base + ni * 16] = hh_;
            dl[base + ni * 16] = bfh(f - bff(hh_));
          }
        } else {
          const int b2 = r / KSEL;
          const int key = r - b2 * KSEL;
          const int hh = (nt - 16) * 2 + wx;
          const long vbase = ((long)(b2 * 16 + hh) * 64) * VP + key;
#pragma unroll
          for (int ni = 0; ni < 4; ni++) {
            const int d = ni * 16 + qi;
            const float f = acc[mi][ni][rr];
            const u16 hh_ = bfh(f);
            vTh[vbase + (long)d * VP] = hh_;
            vTl[vbase + (long)d * VP] = bfh(f - bff(hh_));
          }
        }
      }
    }
  }
}

// ---------- MFMA flash attention (swapped QK^T, lane-local softmax) ----------
__global__ __launch_bounds__(256) void k_attn(
    const u16* __restrict__ qh, const u16* __restrict__ ql,
    const u16* __restrict__ kh, const u16* __restrict__ kl,
    const u16* __restrict__ vh, const u16* __restrict__ vl,
    u16* __restrict__ aoh, u16* __restrict__ aol) {
  __shared__ u16 Qh[64][72], Ql[64][72], Kh[64][72], Kl[64][72],
                 Vh[64][72], Vl[64][72], Ph[64][72];
  const int t = threadIdx.x;
  const int qt = blockIdx.x, h = blockIdx.y, b = blockIdx.z;
  const int w = t >> 6, lane = t & 63;
  const int g = lane >> 4, qi = lane & 15;
  const int sr = t >> 2, sc = (t & 3) * 16;
  const ux4 zz = (ux4){0u, 0u, 0u, 0u};
  {
    const int q_ = qt * 64 + sr;
    if (q_ < KSEL) {
      const long ga = (long)(b * KSEL + q_) * DD + h * 64 + sc;
      *(ux4*)(&Qh[sr][sc]) = *(const ux4*)(qh + ga);
      *(ux4*)(&Qh[sr][sc + 8]) = *(const ux4*)(qh + ga + 8);
      *(ux4*)(&Ql[sr][sc]) = *(const ux4*)(ql + ga);
      *(ux4*)(&Ql[sr][sc + 8]) = *(const ux4*)(ql + ga + 8);
    } else {
      *(ux4*)(&Qh[sr][sc]) = zz; *(ux4*)(&Qh[sr][sc + 8]) = zz;
      *(ux4*)(&Ql[sr][sc]) = zz; *(ux4*)(&Ql[sr][sc + 8]) = zz;
    }
  }
  __syncthreads();
  short8 qf_h[2], qf_l[2];
#pragma unroll
  for (int ks = 0; ks < 2; ks++) {
    qf_h[ks] = *(const short8*)(&Qh[w * 16 + qi][ks * 32 + g * 8]);
    qf_l[ks] = *(const short8*)(&Ql[w * 16 + qi][ks * 32 + g * 8]);
  }
  float m = -1e30f, l = 0.f;
  f32x4 o[4];
#pragma unroll
  for (int dt = 0; dt < 4; dt++) o[dt] = (f32x4){0.f, 0.f, 0.f, 0.f};

  for (int kt = 0; kt < 7; kt++) {
    __syncthreads();
    {
      const int gk = kt * 64 + sr;
      if (gk < KSEL) {
        const long ga = (long)(b * KSEL + gk) * DD + h * 64 + sc;
        *(ux4*)(&Kh[sr][sc]) = *(const ux4*)(kh + ga);
        *(ux4*)(&Kh[sr][sc + 8]) = *(const ux4*)(kh + ga + 8);
        *(ux4*)(&Kl[sr][sc]) = *(const ux4*)(kl + ga);
        *(ux4*)(&Kl[sr][sc + 8]) = *(const ux4*)(kl + ga + 8);
      } else {
        *(ux4*)(&Kh[sr][sc]) = zz; *(ux4*)(&Kh[sr][sc + 8]) = zz;
        *(ux4*)(&Kl[sr][sc]) = zz; *(ux4*)(&Kl[sr][sc + 8]) = zz;
      }
    }
    {
      const long va = ((long)((b * 16 + h) * 64 + sr)) * VP + kt * 64 + sc;
      const int key0 = kt * 64 + sc;
      if (key0 + 15 < KSEL) {
        *(ux4*)(&Vh[sr][sc]) = *(const ux4*)(vh + va);
        *(ux4*)(&Vh[sr][sc + 8]) = *(const ux4*)(vh + va + 8);
        *(ux4*)(&Vl[sr][sc]) = *(const ux4*)(vl + va);
        *(ux4*)(&Vl[sr][sc + 8]) = *(const ux4*)(vl + va + 8);
      } else {
#pragma unroll
        for (int j = 0; j < 16; j++) {
          const bool ok = (key0 + j) < KSEL;
          Vh[sr][sc + j] = ok ? vh[va + j] : (u16)0;
          Vl[sr][sc + j] = ok ? vl[va + j] : (u16)0;
        }
      }
    }
    __syncthreads();
    f32x4 s[4];
#pragma unroll
    for (int mt = 0; mt < 4; mt++) s[mt] = (f32x4){0.f, 0.f, 0.f, 0.f};
#pragma unroll
    for (int ks = 0; ks < 2; ks++) {
#pragma unroll
      for (int mt = 0; mt < 4; mt++) {
        short8 a_h = *(const short8*)(&Kh[mt * 16 + qi][ks * 32 + g * 8]);
        short8 a_l = *(const short8*)(&Kl[mt * 16 + qi][ks * 32 + g * 8]);
        s[mt] = __builtin_amdgcn_mfma_f32_16x16x32_bf16(a_h, qf_h[ks], s[mt], 0, 0, 0);
        s[mt] = __builtin_amdgcn_mfma_f32_16x16x32_bf16(a_h, qf_l[ks], s[mt], 0, 0, 0);
        s[mt] = __builtin_amdgcn_mfma_f32_16x16x32_bf16(a_l, qf_h[ks], s[mt], 0, 0, 0);
      }
    }
    float tmax = -1e30f;
#pragma unroll
    for (int mt = 0; mt < 4; mt++)
#pragma unroll
      for (int r = 0; r < 4; r++) {
        const int key = kt * 64 + mt * 16 + g * 4 + r;
        const float sv = s[mt][r] * 0.125f;
        s[mt][r] = sv;
        if (key < KSEL) tmax = fmaxf(tmax, sv);
      }
    tmax = fmaxf(tmax, __shfl_xor(tmax, 16));
    tmax = fmaxf(tmax, __shfl_xor(tmax, 32));
    const float mn = fmaxf(m, tmax);
    const float scale = __expf(m - mn);
    float part = 0.f;
#pragma unroll
    for (int mt = 0; mt < 4; mt++)
#pragma unroll
      for (int r = 0; r < 4; r++) {
        const int key = kt * 64 + mt * 16 + g * 4 + r;
        const float p = (key < KSEL) ? __expf(s[mt][r] - mn) : 0.f;
        part += p;
        Ph[w * 16 + qi][mt * 16 + g * 4 + r] = bfh(p);
      }
    part += __shfl_xor(part, 16);
    part += __shfl_xor(part, 32);
    l = l * scale + part;
    m = mn;
#pragma unroll
    for (int dt = 0; dt < 4; dt++)
#pragma unroll
      for (int r = 0; r < 4; r++) o[dt][r] *= scale;
#pragma unroll
    for (int ks = 0; ks < 2; ks++) {
      const short8 b_p = *(const short8*)(&Ph[w * 16 + qi][ks * 32 + g * 8]);
#pragma unroll
      for (int dt = 0; dt < 4; dt++) {
        short8 a_h = *(const short8*)(&Vh[dt * 16 + qi][ks * 32 + g * 8]);
        short8 a_l = *(const short8*)(&Vl[dt * 16 + qi][ks * 32 + g * 8]);
        o[dt] = __builtin_amdgcn_mfma_f32_16x16x32_bf16(a_h, b_p, o[dt], 0, 0, 0);
        o[dt] = __builtin_amdgcn_mfma_f32_16x16x32_bf16(a_l, b_p, o[dt], 0, 0, 0);
      }
    }
  }
  // epilogue: O/l -> split-bf16 ao (chunk-swizzled rows for k_oproj DMA)
  const int q_ = qt * 64 + w * 16 + qi;
  if (q_ < KSEL) {
    const float inv = 1.f / l;
    const long rgl = (long)b * KSEL + q_;
    const int swzr = ((int)rgl >> 1) & 3;
#pragma unroll
    for (int dt = 0; dt < 4; dt++) {
      us4 h4, l4;
#pragma unroll
      for (int rr = 0; rr < 4; rr++) {
        const float f = o[dt][rr] * inv;
        const u16 hh_ = bfh(f);
        h4[rr] = hh_;
        l4[rr] = bfh(f - bff(hh_));
      }
      const int chunk = ((dt & 1) << 1) | (g >> 1);
      const long kk = h * 64 + (dt >> 1) * 32 + (long)(chunk ^ swzr) * 8 + (g & 1) * 4;
      *(us4*)(aoh + rgl * DD + kk) = h4;
      *(us4*)(aol + rgl * DD + kk) = l4;
    }
  }
}

// ---------- out-proj + scatter + residual : full-DMA dbuf ----------
__global__ __launch_bounds__(256) void k_oproj(
    const u16* __restrict__ aoh, const u16* __restrict__ aol,
    const u16* __restrict__ wh, const u16* __restrict__ wl,
    const int* __restrict__ sel, const float* __restrict__ x,
    const float* __restrict__ resw, float* __restrict__ y) {
  extern __shared__ u16 sm[];
  u16* AH = sm;
  u16* AL = sm + 8192;
  u16* BH = sm + 16384;
  u16* BL = sm + 24576;
  const int t = threadIdx.x;
  const int nt = blockIdx.x, r0 = blockIdx.y * 128;
  const int w = t >> 6, lane = t & 63;
  const int wy = w >> 1, wx = w & 1;
  const int qi = lane & 15, g = lane >> 4;
  const int swz = (qi >> 1) & 3;
  f32x4 acc[4][4];
#pragma unroll
  for (int i = 0; i < 4; i++)
#pragma unroll
    for (int j = 0; j < 4; j++) acc[i][j] = (f32x4){0.f, 0.f, 0.f, 0.f};

  auto STAGE = [&](int buf, int s) {
#pragma unroll
    for (int i = 0; i < 2; i++) {
      const int row = w * 32 + i * 16 + (lane >> 2);
      int rg = r0 + row;
      rg = rg < MTOT ? rg : MTOT - 1;
      const int ch = (lane & 3) * 8;
      const int lo = w * 1024 + i * 512;
      dma16(aoh + (long)rg * DD + s * 32 + ch, AH + buf * 4096 + lo);
      dma16(aol + (long)rg * DD + s * 32 + ch, AL + buf * 4096 + lo);
      const long wb = ((long)s * DD + nt * 128 + row) * 32 + ch;
      dma16(wh + wb, BH + buf * 4096 + lo);
      dma16(wl + wb, BL + buf * 4096 + lo);
    }
  };

  STAGE(0, 0);
  __syncthreads();
  int cur = 0;
  for (int s = 0; s < 32; s++) {
    if (s < 31) STAGE(cur ^ 1, s + 1);
    short8 a_h[4], a_l[4];
#pragma unroll
    for (int mi = 0; mi < 4; mi++) {
      const int idx = cur * 4096 + (wy * 64 + mi * 16 + qi) * 32 + (g ^ swz) * 8;
      a_h[mi] = *(const short8*)(AH + idx);
      a_l[mi] = *(const short8*)(AL + idx);
    }
#pragma unroll
    for (int ni = 0; ni < 4; ni++) {
      const int idx = cur * 4096 + (wx * 64 + ni * 16 + qi) * 32 + (g ^ swz) * 8;
      short8 b_h = *(const short8*)(BH + idx);
      short8 b_l = *(const short8*)(BL + idx);
#pragma unroll
      for (int mi = 0; mi < 4; mi++) {
        acc[mi][ni] = __builtin_amdgcn_mfma_f32_16x16x32_bf16(a_h[mi], b_h, acc[mi][ni], 0, 0, 0);
        acc[mi][ni] = __builtin_amdgcn_mfma_f32_16x16x32_bf16(a_h[mi], b_l, acc[mi][ni], 0, 0, 0);
        acc[mi][ni] = __builtin_amdgcn_mfma_f32_16x16x32_bf16(a_l[mi], b_h, acc[mi][ni], 0, 0, 0);
      }
    }
    __syncthreads();
    cur ^= 1;
  }
  const float rw = resw[0];
#pragma unroll
  for (int mi = 0; mi < 4; mi++)
#pragma unroll
    for (int rr = 0; rr < 4; rr++) {
      const int r = r0 + wy * 64 + mi * 16 + g * 4 + rr;
      if (r < MTOT) {
        const int bb = r / KSEL;
        const int tok = sel[r];
        const long off = ((long)bb * LL + tok) * DD + nt * 128 + wx * 64 + qi;
#pragma unroll
        for (int ni = 0; ni < 4; ni++)
          y[off + ni * 16] = fmaf(rw, acc[mi][ni][rr], x[off + ni * 16]);
      }
    }
}

extern "C" void kernel_launch(void* const* d_in, const int* in_sizes, int n_in,
                              void* d_out, int out_size, void* d_ws, size_t ws_size,
                              hipStream_t stream) {
  const float* x = (const float*)d_in[0];
  const float* w1 = (const float*)d_in[1];
  const float* b1 = (const float*)d_in[2];
  const float* w2 = (const float*)d_in[3];
  // d_in[4] = b2: constant shift through monotone sigmoid -> irrelevant to top-k
  const float* wqkv = (const float*)d_in[5];
  const float* wout = (const float*)d_in[6];
  const float* resw = (const float*)d_in[7];
  float* y = (float*)d_out;

  char* ws = (char*)d_ws;
  float* z = (float*)(ws);                  // 131072 B
  int* sel = (int*)(ws + 131072);           // 16384 B
  u16* w1h = (u16*)(ws + 147456);           // 524288 B
  u16* w1l = (u16*)(ws + 671744);           // 524288 B
  u16* wqh = (u16*)(ws + 1196032);          // 6291456 B
  u16* wql = (u16*)(ws + 7487488);          // 6291456 B
  u16* woh = (u16*)(ws + 13778944);         // 2097152 B
  u16* wol = (u16*)(ws + 15876096);         // 2097152 B
  u16* qh = (u16*)(ws + 17973248);          // 6701056 B
  u16* ql = (u16*)(ws + 24674304);          // 6701056 B
  u16* kh = (u16*)(ws + 31375360);          // 6701056 B
  u16* kl = (u16*)(ws + 38076416);          // 6701056 B
  u16* vTh = (u16*)(ws + 44777472);         // 7340032 B
  u16* vTl = (u16*)(ws + 52117504);         // 7340032 B
  u16* xsh = (u16*)(ws + 59457536);         // 6701056 B (aliased: ao hi after qkv)
  u16* xsl = (u16*)(ws + 66158592);         // 6701056 B (aliased: ao lo after qkv)
  u16* aoh = xsh;  // xs dead after k_qkv; stream-ordered reuse
  u16* aol = xsl;

  hipFuncSetAttribute(reinterpret_cast<const void*>(k_score),
                      hipFuncAttributeMaxDynamicSharedMemorySize, 104448);
  hipFuncSetAttribute(reinterpret_cast<const void*>(k_qkv),
                      hipFuncAttributeMaxDynamicSharedMemorySize, 65536);
  hipFuncSetAttribute(reinterpret_cast<const void*>(k_oproj),
                      hipFuncAttributeMaxDynamicSharedMemorySize, 65536);

  k_prep<<<dim3(1, 32), 256, 0, stream>>>(w1, 256, w1h, w1l);
  k_prep<<<dim3(12, 32), 256, 0, stream>>>(wqkv, NT3, wqh, wql);
  k_prep<<<dim3(4, 32), 256, 0, stream>>>(wout, DD, woh, wol);
  k_score<<<256, 512, 104448, stream>>>(x, w1h, w1l, b1, w2, z, y);
  k_topk<<<BB, 1024, 0, stream>>>(z, sel);
  k_xsel<<<409, 256, 0, stream>>>(x, sel, xsh, xsl);
  k_qkv<<<dim3(24, 26), 256, 65536, stream>>>(xsh, xsl, wqh, wql, qh, ql, kh, kl, vTh, vTl);
  k_attn<<<dim3(7, HH, BB), 256, 0, stream>>>(qh, ql, kh, kl, vTh, vTl, aoh, aol);
  k_oproj<<<dim3(8, 26), 256, 65536, stream>>>(aoh, aol, woh, wol, sel, x, resw, y);
}